// Round 8
// baseline (251.973 us; speedup 1.0000x reference)
//
#include <hip/hip_runtime.h>
#include <hip/hip_bf16.h>

#define NSUBJ 64
#define CIN   295
#define DD    270
#define TT    2048
#define BB    128

// Wf tiled layout: [s][mt:3][ks:10][kq:4][m:96][k8:8] (bf16, c = ks*32+kq*8+k8,
// e = mt*96 + m). Column c==295 holds fused bias (Ws@b1); X[295] synthesized 1.0
#define WF_PER_S  92160   // 3*10*4*96*8
#define WF_PER_MT 30720   // 10*4*96*8
#define WF_PER_KS 3072    // 4*96*8
#define WF_PER_KQ 768     // 96*8
// W1t tiled layout: [ks:9][kq:4][c:320][8] bf16 (d = ks*32+kq*8+k8), c=295 -> b1
#define W1T_PER_KS 10240  // 4*320*8

typedef __attribute__((ext_vector_type(8))) short bf16x8;
typedef __attribute__((ext_vector_type(4))) float f32x4;
typedef unsigned short u16;

__device__ __forceinline__ u16 f2bf(float f) {
    return __bfloat16_as_ushort(__float2bfloat16(f));   // RNE; compiler may pair
}

// async global->LDS, 16B/lane (HW-verified width); lds dest = base + lane*16
__device__ __forceinline__ void glds16(const u16* g, u16* lds_base) {
    __builtin_amdgcn_global_load_lds(
        (const __attribute__((address_space(1))) unsigned int*)g,
        (__attribute__((address_space(3))) unsigned int*)lds_base, 16, 0, 0);
}

#define WAITV(N) asm volatile("s_waitcnt vmcnt(" #N ")" ::: "memory")
#define WAITL()  asm volatile("s_waitcnt lgkmcnt(0)" ::: "memory")
#define BAR()    __builtin_amdgcn_s_barrier()
#define SB()     __builtin_amdgcn_sched_barrier(0)

// ---------------------------------------------------------------------------
// W1 [270][295] f32 (+ b1 as c=295) -> W1t bf16 tiled [ks][kq][c:320][8]
// ---------------------------------------------------------------------------
__global__ __launch_bounds__(256) void k_prep_w1(const float* __restrict__ W1,
                                                 const float* __restrict__ b1,
                                                 u16* __restrict__ W1t)
{
    const int idx = blockIdx.x * 256 + threadIdx.x;      // 92160 total
    const int ks = idx / W1T_PER_KS;
    const int r  = idx - ks * W1T_PER_KS;
    const int kq = r / 2560;
    const int c  = (r - kq * 2560) >> 3;   // 0..319
    const int k8 = r & 7;
    const int d  = ks * 32 + kq * 8 + k8;
    float v = 0.f;
    if (d < DD) {
        if (c < CIN) v = W1[d * CIN + c];
        else if (c == CIN) v = b1[d];
    }
    W1t[idx] = f2bf(v);
}

// ---------------------------------------------------------------------------
// Wf[s] = bf16(Ws[s] @ [W1|b1]) in k_main's tiled A layout
// grid (3 mt, 64 s), block 256 = 4 waves (2M x 2N), tile 96e x 320c, K=288
// ---------------------------------------------------------------------------
__global__ __launch_bounds__(256, 1) void k_fuse_w(const float* __restrict__ Ws,
                                                   const u16* __restrict__ W1t,
                                                   u16* __restrict__ Wf)
{
    __shared__ u16 Aw[3072];    // [kq:4][96][8]
    __shared__ u16 Bw[10240];   // [kq:4][320][8]
    const int tid = threadIdx.x, lane = tid & 63, wid = tid >> 6;
    const int wm = wid >> 1, wn = wid & 1;
    const int mt = blockIdx.x, s = blockIdx.y;
    const int e0 = mt * 96;
    const float* Wsb = Ws + (size_t)s * DD * DD;

    f32x4 acc[3][10];
#pragma unroll
    for (int i = 0; i < 3; ++i)
#pragma unroll
        for (int j = 0; j < 10; ++j) acc[i][j] = (f32x4){0.f, 0.f, 0.f, 0.f};

    for (int ks = 0; ks < 9; ++ks) {
        const int k0 = ks * 32;
#pragma unroll
        for (int ci = 0; ci < 3; ++ci) {
            const int id = tid + ci * 256;
            const int m = id >> 3, q = id & 7;
            const int e = e0 + m, d = k0 + q * 4;
            float2 v01 = {0.f, 0.f}, v23 = {0.f, 0.f};
            if (e < DD) {
                if (d < DD)     v01 = *(const float2*)(Wsb + (size_t)e * DD + d);
                if (d + 2 < DD) v23 = *(const float2*)(Wsb + (size_t)e * DD + d + 2);
            }
            ushort4 h;
            h.x = f2bf(v01.x); h.y = f2bf(v01.y); h.z = f2bf(v23.x); h.w = f2bf(v23.y);
            *(ushort4*)(&Aw[(q >> 1) * 768 + m * 8 + (q & 1) * 4]) = h;
        }
#pragma unroll
        for (int k5 = 0; k5 < 5; ++k5) {
            const int seg = wid * 5 + k5;
            glds16(W1t + (size_t)ks * W1T_PER_KS + seg * 512 + lane * 8, &Bw[seg * 512]);
        }
        __syncthreads();
        bf16x8 af[3];
#pragma unroll
        for (int i = 0; i < 3; ++i)
            af[i] = *(const bf16x8*)(&Aw[(lane >> 4) * 768 + (wm * 48 + i * 16 + (lane & 15)) * 8]);
#pragma unroll
        for (int j = 0; j < 10; ++j) {
            const bf16x8 bfj = *(const bf16x8*)(&Bw[(lane >> 4) * 2560 + (wn * 160 + j * 16 + (lane & 15)) * 8]);
#pragma unroll
            for (int i = 0; i < 3; ++i)
                acc[i][j] = __builtin_amdgcn_mfma_f32_16x16x32_bf16(af[i], bfj, acc[i][j], 0, 0, 0);
        }
        __syncthreads();
    }
    const int rb = (lane >> 4) * 4, cc = lane & 15;
#pragma unroll
    for (int i = 0; i < 3; ++i) {
#pragma unroll
        for (int r = 0; r < 4; ++r) {
            const int e = e0 + wm * 48 + i * 16 + rb + r;
            const int m = e - e0;
#pragma unroll
            for (int j = 0; j < 10; ++j) {
                const int c = wn * 160 + j * 16 + cc;
                Wf[(size_t)s * WF_PER_S + (size_t)mt * WF_PER_MT + (c >> 5) * WF_PER_KS
                   + ((c >> 3) & 3) * WF_PER_KQ + m * 8 + (c & 7)] = f2bf(acc[i][j][r]);
            }
        }
    }
}

// ---------------------------------------------------------------------------
// out[b] = Wf[subj[b]] @ [X[b]; 1]
// 1-D grid 12288 -> XCD-chunked (b, nt, mt) with mt innermost (X L2 sharing).
// block 256 = 4 waves (2M x 2N), tile 96e x 64t, K=320.
// DEPTH-3 pipeline: LDS triple-buffered; X loads 3-ahead (3 reg bufs),
// glds 2-ahead. Steady queue at step k entry: [X(k+1) 8, G(k+1) 2, X(k+2) 8];
// step issues G(k+2), X(k+3); single WAITV(18) retires X(k+1)+G(k+1).
// Cover: glds ~1.7 steps, X ~2.5 steps.
// ---------------------------------------------------------------------------
__global__ __launch_bounds__(256, 5) void k_main(const float* __restrict__ X,
                                                 const int* __restrict__ subj,
                                                 const u16* __restrict__ Wf,
                                                 float* __restrict__ out)
{
    __shared__ u16 Am[3][3072];   // [kq:4][96][8] = 6KB per buffer
    __shared__ u16 Bm[3][2048];   // [kq:4][64][8] = 4KB per buffer
    const int tid = threadIdx.x, lane = tid & 63, wid = tid >> 6;
    const int wm = wid >> 1, wn = wid & 1;
    // XCD-chunked swizzle: 12288 blocks, 1536 consecutive work-items per XCD
    const int hw = blockIdx.x;
    const int w  = (hw & 7) * 1536 + (hw >> 3);
    const int b  = w / 96;
    const int r0 = w - b * 96;
    const int nt = r0 / 3, mt = r0 - nt * 3;
    const int t0 = nt * 64;
    const int s = subj[b];
    const float* Xb = X + (size_t)b * CIN * TT;
    const u16* WfA = Wf + (size_t)s * WF_PER_S + (size_t)mt * WF_PER_MT;
    const int bn = tid & 63, bkq = tid >> 6;

    f32x4 acc[3][2];
#pragma unroll
    for (int i = 0; i < 3; ++i)
#pragma unroll
        for (int j = 0; j < 2; ++j) acc[i][j] = (f32x4){0.f, 0.f, 0.f, 0.f};

    float xr0[8], xr1[8], xr2[8];

    // exactly 8 loads, distinct in-bounds addresses (clamped c-33 fallback)
#define LOADB(KS, XR, CL)                                                   \
    {                                                                       \
        _Pragma("unroll")                                                   \
        for (int q = 0; q < 8; ++q) {                                       \
            const int c = (KS) * 32 + bkq * 8 + q;                          \
            const int cl = ((CL) && c >= CIN) ? (c - 33) : c;               \
            XR[q] = Xb[(size_t)cl * TT + t0 + bn];                          \
        }                                                                   \
    }
#define WRITEB(KS, XR)                                                      \
    {                                                                       \
        bf16x8 h;                                                           \
        _Pragma("unroll")                                                   \
        for (int q = 0; q < 8; ++q) {                                       \
            const int c = (KS) * 32 + bkq * 8 + q;                          \
            u16 v = f2bf(XR[q]);                                            \
            if (c >= CIN) v = (c == CIN) ? (u16)0x3F80 : (u16)0;            \
            h[q] = (short)v;                                                \
        }                                                                   \
        *(bf16x8*)(&Bm[(KS) % 3][bkq * 512 + bn * 8]) = h;                  \
    }
    // uniform: 2 glds16 per wave; 6 real segs of 512 el (1KB); wave 3 dups 0,1
#define STAGEA(KS)                                                          \
    {                                                                       \
        _Pragma("unroll")                                                   \
        for (int k2 = 0; k2 < 2; ++k2) {                                    \
            int seg = wid * 2 + k2;                                         \
            if (seg >= 6) seg -= 6;                                         \
            glds16(WfA + (size_t)(KS) * WF_PER_KS + seg * 512 + lane * 8,   \
                   &Am[(KS) % 3][seg * 512]);                               \
        }                                                                   \
    }
#define COMPUTE(CUR)                                                        \
    {                                                                       \
        bf16x8 bfr[2];                                                      \
        _Pragma("unroll")                                                   \
        for (int j = 0; j < 2; ++j)                                         \
            bfr[j] = *(const bf16x8*)(&Bm[(CUR) % 3][(lane >> 4) * 512 + (wn * 32 + j * 16 + (lane & 15)) * 8]); \
        _Pragma("unroll")                                                   \
        for (int i = 0; i < 3; ++i) {                                       \
            const bf16x8 af = *(const bf16x8*)(&Am[(CUR) % 3][(lane >> 4) * 768 + (wm * 48 + i * 16 + (lane & 15)) * 8]); \
            acc[i][0] = __builtin_amdgcn_mfma_f32_16x16x32_bf16(af, bfr[0], acc[i][0], 0, 0, 0); \
            acc[i][1] = __builtin_amdgcn_mfma_f32_16x16x32_bf16(af, bfr[1], acc[i][1], 0, 0, 0); \
        }                                                                   \
    }

    // ---- prologue: issue order X0, G0, X1, G1, X2  (queue = 28) ----
    LOADB(0, xr0, 0); SB();
    STAGEA(0);        SB();
    LOADB(1, xr1, 0); SB();
    STAGEA(1);        SB();
    LOADB(2, xr2, 0); SB();
    WAITV(20);                 // X0 retired
    WRITEB(0, xr0);
    WAITV(18);                 // G0 retired; [X1,G1,X2]=18 in flight
    WAITL(); BAR();

    // ---- steady steps k=0..6: issue G(k+2), X(k+3); WAITV(18) ----
#define STEP(KS, XLD, XWR, CL)                                              \
    {                                                                       \
        STAGEA((KS) + 2);         SB();                                     \
        LOADB((KS) + 3, XLD, CL); SB();                                     \
        COMPUTE(KS);                                                        \
        WAITV(18);   /* X(KS+1)+G(KS+1) retired; 18 in flight */            \
        WRITEB((KS) + 1, XWR);                                              \
        WAITL(); BAR();                                                     \
    }
    STEP(0, xr0, xr1, 0);
    STEP(1, xr1, xr2, 0);
    STEP(2, xr2, xr0, 0);
    STEP(3, xr0, xr1, 0);
    STEP(4, xr1, xr2, 0);
    STEP(5, xr2, xr0, 0);
    STEP(6, xr0, xr1, 1);      // LOADB(9): c up to 319 -> clamp
    // ---- step 7: stage tile 9, no more X issues ----
    STAGEA(9); SB();
    COMPUTE(7);
    WAITV(10);                 // X8+G8 retired; [X9,G9]=10 in flight
    WRITEB(8, xr2);
    WAITL(); BAR();
    // ---- step 8 ----
    COMPUTE(8);
    WAITV(0);                  // X9+G9 retired
    WRITEB(9, xr0);
    WAITL(); BAR();
    // ---- step 9 ----
    COMPUTE(9);

    // epilogue: C/D layout col=lane&15, row=(lane>>4)*4+reg (bias fused in K)
    const int rb = (lane >> 4) * 4, cc = lane & 15;
#pragma unroll
    for (int i = 0; i < 3; ++i) {
#pragma unroll
        for (int r = 0; r < 4; ++r) {
            const int e = mt * 96 + wm * 48 + i * 16 + rb + r;
            if (e < DD) {
#pragma unroll
                for (int j = 0; j < 2; ++j) {
                    const int t = t0 + wn * 32 + j * 16 + cc;
                    out[((size_t)b * DD + e) * TT + t] = acc[i][j][r];
                }
            }
        }
    }
#undef LOADB
#undef WRITEB
#undef STAGEA
#undef COMPUTE
#undef STEP
}

extern "C" void kernel_launch(void* const* d_in, const int* in_sizes, int n_in,
                              void* d_out, int out_size, void* d_ws, size_t ws_size,
                              hipStream_t stream) {
    const float* X    = (const float*)d_in[0];
    const int*   subj = (const int*)d_in[1];
    const float* W1   = (const float*)d_in[2];
    const float* b1   = (const float*)d_in[3];
    const float* Ws   = (const float*)d_in[4];
    float* out = (float*)d_out;

    u16* Wf  = (u16*)d_ws;                                         // 11,796,480 B
    u16* W1t = (u16*)((char*)d_ws + (size_t)NSUBJ * WF_PER_S * 2); // + 184,320 B

    k_prep_w1<<<dim3(360), 256, 0, stream>>>(W1, b1, W1t);
    k_fuse_w<<<dim3(3, NSUBJ), 256, 0, stream>>>(Ws, W1t, Wf);
    k_main<<<dim3(3 * (TT / 64) * BB), 256, 0, stream>>>(X, subj, Wf, out);
}

// Round 9
// 192.473 us; speedup vs baseline: 1.3091x; 1.3091x over previous
//
#include <hip/hip_runtime.h>
#include <hip/hip_bf16.h>

#define NSUBJ 64
#define CIN   295
#define DD    270
#define TT    2048
#define BB    128

// Wf tiled layout: [s][ks:10][kq:4][m:288][k8:8]  (bf16, c = ks*32+kq*8+k8)
// column c==295 holds the fused bias (Ws@b1); B-side c==295 synthesized as 1.0
#define WF_PER_S  92160   // 10*4*288*8
#define WF_PER_KS 9216    // 4*288*8
// W1t tiled layout: [ks:9][kq:4][c:320][8] bf16 (d = ks*32+kq*8+k8), c=295 -> b1
#define W1T_PER_KS 10240  // 4*320*8

typedef __attribute__((ext_vector_type(8))) short bf16x8;
typedef __attribute__((ext_vector_type(4))) float f32x4;
typedef unsigned short u16;

__device__ __forceinline__ u16 f2bf(float f) {
    return __bfloat16_as_ushort(__float2bfloat16(f));   // RNE HW cvt
}

// async global->LDS, 16B/lane; lds dest = base + lane*16 (linear, wave-uniform base)
__device__ __forceinline__ void glds16(const void* g, void* lds_base) {
    __builtin_amdgcn_global_load_lds(
        (const __attribute__((address_space(1))) unsigned int*)g,
        (__attribute__((address_space(3))) unsigned int*)lds_base, 16, 0, 0);
}

// ---------------------------------------------------------------------------
// W1 [270][295] f32 (+ b1 as c=295) -> W1t bf16 tiled [ks][kq][c:320][8]
// ---------------------------------------------------------------------------
__global__ __launch_bounds__(256) void k_prep_w1(const float* __restrict__ W1,
                                                 const float* __restrict__ b1,
                                                 u16* __restrict__ W1t)
{
    const int idx = blockIdx.x * 256 + threadIdx.x;      // 92160 total
    const int ks = idx / W1T_PER_KS;
    const int r  = idx - ks * W1T_PER_KS;
    const int kq = r / 2560;
    const int c  = (r - kq * 2560) >> 3;   // 0..319
    const int k8 = r & 7;
    const int d  = ks * 32 + kq * 8 + k8;
    float v = 0.f;
    if (d < DD) {
        if (c < CIN) v = W1[d * CIN + c];
        else if (c == CIN) v = b1[d];
    }
    W1t[idx] = f2bf(v);
}

// ---------------------------------------------------------------------------
// Wf[s] = bf16(Ws[s] @ [W1|b1]) in k_main's tiled A layout
// grid (3 mt, 64 s), block 256 = 4 waves (2M x 2N), tile 96e x 320c, K=288
// ---------------------------------------------------------------------------
__global__ __launch_bounds__(256, 1) void k_fuse_w(const float* __restrict__ Ws,
                                                   const u16* __restrict__ W1t,
                                                   u16* __restrict__ Wf)
{
    __shared__ u16 Aw[3072];    // [kq:4][96][8]
    __shared__ u16 Bw[10240];   // [kq:4][320][8]
    const int tid = threadIdx.x, lane = tid & 63, wid = tid >> 6;
    const int wm = wid >> 1, wn = wid & 1;
    const int mt = blockIdx.x, s = blockIdx.y;
    const int e0 = mt * 96;
    const float* Wsb = Ws + (size_t)s * DD * DD;

    f32x4 acc[3][10];
#pragma unroll
    for (int i = 0; i < 3; ++i)
#pragma unroll
        for (int j = 0; j < 10; ++j) acc[i][j] = (f32x4){0.f, 0.f, 0.f, 0.f};

    for (int ks = 0; ks < 9; ++ks) {
        const int k0 = ks * 32;
#pragma unroll
        for (int ci = 0; ci < 3; ++ci) {
            const int id = tid + ci * 256;
            const int m = id >> 3, q = id & 7;
            const int e = e0 + m, d = k0 + q * 4;
            float2 v01 = {0.f, 0.f}, v23 = {0.f, 0.f};
            if (e < DD) {
                if (d < DD)     v01 = *(const float2*)(Wsb + (size_t)e * DD + d);
                if (d + 2 < DD) v23 = *(const float2*)(Wsb + (size_t)e * DD + d + 2);
            }
            ushort4 h;
            h.x = f2bf(v01.x); h.y = f2bf(v01.y); h.z = f2bf(v23.x); h.w = f2bf(v23.y);
            *(ushort4*)(&Aw[(q >> 1) * 768 + m * 8 + (q & 1) * 4]) = h;
        }
#pragma unroll
        for (int k5 = 0; k5 < 5; ++k5) {
            const int seg = wid * 5 + k5;
            glds16(W1t + (size_t)ks * W1T_PER_KS + seg * 512 + lane * 8, &Bw[seg * 512]);
        }
        __syncthreads();
        bf16x8 af[3];
#pragma unroll
        for (int i = 0; i < 3; ++i)
            af[i] = *(const bf16x8*)(&Aw[(lane >> 4) * 768 + (wm * 48 + i * 16 + (lane & 15)) * 8]);
#pragma unroll
        for (int j = 0; j < 10; ++j) {
            const bf16x8 bfj = *(const bf16x8*)(&Bw[(lane >> 4) * 2560 + (wn * 160 + j * 16 + (lane & 15)) * 8]);
#pragma unroll
            for (int i = 0; i < 3; ++i)
                acc[i][j] = __builtin_amdgcn_mfma_f32_16x16x32_bf16(af[i], bfj, acc[i][j], 0, 0, 0);
        }
        __syncthreads();
    }
    const int rb = (lane >> 4) * 4, cc = lane & 15;
#pragma unroll
    for (int i = 0; i < 3; ++i) {
#pragma unroll
        for (int r = 0; r < 4; ++r) {
            const int e = e0 + wm * 48 + i * 16 + rb + r;
#pragma unroll
            for (int j = 0; j < 10; ++j) {
                const int c = wn * 160 + j * 16 + cc;
                Wf[(size_t)s * WF_PER_S + (c >> 5) * WF_PER_KS + ((c >> 3) & 3) * 2304
                   + e * 8 + (c & 7)] = f2bf(acc[i][j][r]);
            }
        }
    }
}

// ---------------------------------------------------------------------------
// out[b] = Wf[subj[b]] @ [X[b]; 1]
// grid (32 nt, 128 b), block 256 = 4 waves (2M x 2N), tile 288e x 64t, K=320.
// Pure-glds16 m97 structure: double-buffered LDS, STAGE(k+1) -> COMPUTE(k) ->
// __syncthreads(), one barrier/step.  X staged as raw f32 [32c][64t] with a
// row-dependent t-XOR swizzle applied on the GLOBAL source address (LDS dest
// linear); compute reads it transposed via conflict-free (2-way) ds_read_b32
// and converts to bf16 in-register.
//   stored[row][t] = X[ks*32+row][t0 + (t ^ (((row>>3)&3)<<4))]
// ---------------------------------------------------------------------------
__global__ __launch_bounds__(256, 2) void k_main(const float* __restrict__ X,
                                                 const int* __restrict__ subj,
                                                 const u16* __restrict__ Wf,
                                                 float* __restrict__ out)
{
    __shared__ u16   Am[2][9216];    // [kq:4][288][8] bf16, 18KB each
    __shared__ float Xm[2][2048];    // [c:32][t:64] f32 (swizzled), 8KB each
    const int tid = threadIdx.x, lane = tid & 63, wid = tid >> 6;
    const int wm = wid >> 1, wn = wid & 1;
    const int nt = blockIdx.x, b = blockIdx.y;
    const int t0 = nt * 64;
    const int s = subj[b];
    const float* Xb = X + (size_t)b * CIN * TT;
    const u16* WfA = Wf + (size_t)s * WF_PER_S;
    const int g = lane >> 4;          // kq group 0..3

    f32x4 acc[9][2];
#pragma unroll
    for (int i = 0; i < 9; ++i)
#pragma unroll
        for (int j = 0; j < 2; ++j) acc[i][j] = (f32x4){0.f, 0.f, 0.f, 0.f};

    // A: 18 segs x 1KB; waves 0,1 stage 5, waves 2,3 stage 4 (no vmcnt counting)
#define STAGEA(KS)                                                          \
    {                                                                       \
        _Pragma("unroll")                                                   \
        for (int k5 = 0; k5 < 5; ++k5) {                                    \
            const int seg = wid + 4 * k5;                                   \
            if (seg < 18)                                                   \
                glds16(WfA + (size_t)(KS) * WF_PER_KS + seg * 512 + lane * 8,\
                       &Am[(KS) & 1][seg * 512]);                           \
        }                                                                   \
    }
    // X: 8 segs x 1KB (4 rows of 64 f32 each); wave w stages segs 2w, 2w+1.
    // Per-lane source col pre-swizzled (16B-chunk XOR); row clamped to <295.
#define STAGEX(KS)                                                          \
    {                                                                       \
        _Pragma("unroll")                                                   \
        for (int k2 = 0; k2 < 2; ++k2) {                                    \
            const int seg = wid * 2 + k2;                                   \
            const int cr0 = (KS) * 32 + seg * 4 + g;                        \
            const int cr  = (cr0 < CIN) ? cr0 : (CIN - 1);                  \
            const int sc  = (lane & 15) ^ (((seg >> 1) & 3) << 2);          \
            glds16(Xb + (size_t)cr * TT + t0 + sc * 4,                      \
                   &Xm[(KS) & 1][seg * 256]);                               \
        }                                                                   \
    }
    // Build 2 B-frags from Xm (transposed read, 2-way banks, bf16 cvt in-reg)
#define COMPUTE(KS, LAST)                                                   \
    {                                                                       \
        const float* Xc = &Xm[(KS) & 1][0];                                 \
        bf16x8 bfr[2];                                                      \
        _Pragma("unroll")                                                   \
        for (int j = 0; j < 2; ++j) {                                       \
            const int tsw = (wn * 32 + j * 16 + (lane & 15)) ^ (g << 4);    \
            bf16x8 bb;                                                      \
            _Pragma("unroll")                                               \
            for (int q = 0; q < 8; ++q) {                                   \
                float v = Xc[(g * 8 + q) * 64 + tsw];                       \
                if (LAST) {                                                 \
                    if (q == 7)      v = (g == 0) ? 1.0f : 0.0f;            \
                    else if (g > 0)  v = 0.0f;                              \
                }                                                           \
                bb[q] = (short)f2bf(v);                                     \
            }                                                               \
            bfr[j] = bb;                                                    \
        }                                                                   \
        _Pragma("unroll")                                                   \
        for (int i = 0; i < 9; ++i) {                                       \
            const bf16x8 af = *(const bf16x8*)(&Am[(KS) & 1][g * 2304 + (wm * 144 + i * 16 + (lane & 15)) * 8]); \
            acc[i][0] = __builtin_amdgcn_mfma_f32_16x16x32_bf16(af, bfr[0], acc[i][0], 0, 0, 0); \
            acc[i][1] = __builtin_amdgcn_mfma_f32_16x16x32_bf16(af, bfr[1], acc[i][1], 0, 0, 0); \
        }                                                                   \
    }

    // prologue
    STAGEA(0); STAGEX(0);
    __syncthreads();

#pragma unroll
    for (int ks = 0; ks < 10; ++ks) {
        if (ks < 9) { STAGEA(ks + 1); STAGEX(ks + 1); }
        COMPUTE(ks, (ks == 9));
        __syncthreads();
    }

    // epilogue: C/D layout col=lane&15, row=(lane>>4)*4+reg (bias fused in K)
    const int rb = g * 4, cc = lane & 15;
#pragma unroll
    for (int i = 0; i < 9; ++i) {
#pragma unroll
        for (int r = 0; r < 4; ++r) {
            const int e = wm * 144 + i * 16 + rb + r;
            if (e < DD) {
#pragma unroll
                for (int j = 0; j < 2; ++j) {
                    const int t = t0 + wn * 32 + j * 16 + cc;
                    out[((size_t)b * DD + e) * TT + t] = acc[i][j][r];
                }
            }
        }
    }
#undef STAGEA
#undef STAGEX
#undef COMPUTE
}

extern "C" void kernel_launch(void* const* d_in, const int* in_sizes, int n_in,
                              void* d_out, int out_size, void* d_ws, size_t ws_size,
                              hipStream_t stream) {
    const float* X    = (const float*)d_in[0];
    const int*   subj = (const int*)d_in[1];
    const float* W1   = (const float*)d_in[2];
    const float* b1   = (const float*)d_in[3];
    const float* Ws   = (const float*)d_in[4];
    float* out = (float*)d_out;

    u16* Wf  = (u16*)d_ws;                                         // 11,796,480 B
    u16* W1t = (u16*)((char*)d_ws + (size_t)NSUBJ * WF_PER_S * 2); // + 184,320 B

    k_prep_w1<<<dim3(360), 256, 0, stream>>>(W1, b1, W1t);
    k_fuse_w<<<dim3(3, NSUBJ), 256, 0, stream>>>(Ws, W1t, Wf);
    k_main<<<dim3(TT / 64, BB), 256, 0, stream>>>(X, subj, Wf, out);
}